// Round 1
// baseline (860.571 us; speedup 1.0000x reference)
//
#include <hip/hip_runtime.h>
#include <cfloat>
#include <cstddef>

#define B_ 32
#define C_ 8192
#define D_ 256
#define K_ 512
#define NCH 64
#define CPB (C_ / NCH) /* 128 c's per chunk */
#define CBLK 16        /* c's per block in key kernel */

// ---------------- k1: column reduce over C (sum, min, 2nd-min) ----------------
// grid = B*NCH blocks, 256 threads. Thread t: d4 = t&63 (float4 of d), coff = t>>6.
// Each wave (64 lanes, same coff) loads one full 1KB row of acd per iteration.
__global__ __launch_bounds__(256) void k1_colreduce(const float* __restrict__ acd,
                                                    float* __restrict__ psum,
                                                    float* __restrict__ pm1,
                                                    float* __restrict__ pm2) {
    const int t = threadIdx.x;
    const int blk = blockIdx.x;
    const int b = blk / NCH, ch = blk % NCH;
    const int d4 = t & 63;
    const int coff = t >> 6;

    const float4* src = (const float4*)(acd + ((size_t)b * C_ + (size_t)ch * CPB) * D_);

    float4 s  = make_float4(0.f, 0.f, 0.f, 0.f);
    float4 m1 = make_float4(FLT_MAX, FLT_MAX, FLT_MAX, FLT_MAX);
    float4 m2 = m1;

#define UPD3(f) { s.f += x.f; float mx = fmaxf(m1.f, x.f); m2.f = fminf(m2.f, mx); m1.f = fminf(m1.f, x.f); }
#pragma unroll 4
    for (int r = coff; r < CPB; r += 4) {
        float4 x = src[(size_t)r * 64 + d4];
        UPD3(x) UPD3(y) UPD3(z) UPD3(w)
    }
#undef UPD3

    __shared__ float4 ls[256];
    __shared__ float4 l1[256];
    __shared__ float4 l2[256];
    ls[t] = s; l1[t] = m1; l2[t] = m2;
    __syncthreads();

    if (t < 64) {
        float4 S = ls[t], M1 = l1[t], M2 = l2[t];
#define CMB(f) { S.f += s2.f; float mx = fmaxf(M1.f, a1.f); M2.f = fminf(fminf(M2.f, a2.f), mx); M1.f = fminf(M1.f, a1.f); }
#pragma unroll
        for (int j = 64; j < 256; j += 64) {
            float4 s2 = ls[t + j], a1 = l1[t + j], a2 = l2[t + j];
            CMB(x) CMB(y) CMB(z) CMB(w)
        }
#undef CMB
        size_t o = ((size_t)b * NCH + ch) * 64 + t;
        ((float4*)psum)[o] = S;
        ((float4*)pm1)[o] = M1;
        ((float4*)pm2)[o] = M2;
    }
}

// ---------------- k2: combine chunks; density/total/overly-flag per (b,d) -----
__global__ __launch_bounds__(256) void k2_finalize(const float* __restrict__ psum,
                                                   const float* __restrict__ pm1,
                                                   const float* __restrict__ pm2,
                                                   const float* __restrict__ weight,
                                                   const float* __restrict__ mu,
                                                   const float* __restrict__ var,
                                                   const int* __restrict__ labels,
                                                   float* __restrict__ dens_o,
                                                   float* __restrict__ tot_o,
                                                   float* __restrict__ ofl_o) {
    const int b = blockIdx.x, d = threadIdx.x;
    float sum = 0.f, m1 = FLT_MAX, m2 = FLT_MAX;
    for (int ch = 0; ch < NCH; ch++) {
        size_t o = ((size_t)b * NCH + ch) * D_ + d;
        float cs = psum[o], c1 = pm1[o], c2 = pm2[o];
        sum += cs;
        m2 = fminf(fminf(m2, c2), fmaxf(m1, c1));
        m1 = fminf(m1, c1);
    }
    const int lab = labels[b];
    const float sw = weight[(size_t)lab * D_ + d];
    const float diff = sw - mu[b * D_ + d];
    const float v = var[b * D_ + d];
    const float dens = expf(-(diff * diff) / (2.0f * v));
    const float tot = fmaxf(sum, 1e-8f);
    // minv - maxv == secondmin - min; >= 0.2*total  (nt holds for all c != argmin)
    const float o_ = (m2 - m1 >= 0.2f * tot) ? 1.0f : 0.0f;
    dens_o[b * D_ + d] = dens;
    tot_o[b * D_ + d] = tot;
    ofl_o[b * D_ + d] = o_;
}

// ---------------- k3: distance keys |w_c|^2 - 2 s_b . w_c  --------------------
// grid = C/CBLK blocks of 256. LDS-tiled; stride 257 padding avoids 32-way bank conflict.
__global__ __launch_bounds__(256) void k3_keys(const float* __restrict__ weight,
                                               const int* __restrict__ labels,
                                               float* __restrict__ keys) {
    __shared__ float s_s[32 * 257];
    __shared__ float s_w[CBLK * 257];
    __shared__ float s_wsq[CBLK];
    __shared__ float ktile[CBLK * 33];
    const int t = threadIdx.x;
    const int c0 = blockIdx.x * CBLK;

    for (int i = t; i < 32 * D_; i += 256) {
        int bb = i >> 8, d = i & 255;
        s_s[bb * 257 + d] = weight[(size_t)labels[bb] * D_ + d];
    }
    for (int i = t; i < CBLK * D_; i += 256) {
        int cc = i >> 8, d = i & 255;
        s_w[cc * 257 + d] = weight[(size_t)(c0 + cc) * D_ + d];
    }
    __syncthreads();

    const int b = t & 31, cg = t >> 5;
    const int cc0 = cg, cc1 = cg + 8;
    float acc0 = 0.f, acc1 = 0.f, w0 = 0.f, w1 = 0.f;
    for (int d = 0; d < D_; d++) {
        float sv = s_s[b * 257 + d];
        float wa = s_w[cc0 * 257 + d], wb = s_w[cc1 * 257 + d];
        acc0 += sv * wa;
        acc1 += sv * wb;
        if (b == 0) { w0 += wa * wa; w1 += wb * wb; }
    }
    if (b == 0) { s_wsq[cc0] = w0; s_wsq[cc1] = w1; }
    __syncthreads();
    ktile[cc0 * 33 + b] = s_wsq[cc0] - 2.0f * acc0;
    ktile[cc1 * 33 + b] = s_wsq[cc1] - 2.0f * acc1;
    __syncthreads();
    for (int i = t; i < 32 * CBLK; i += 256) {
        int bb = i >> 4, cc = i & 15;
        keys[(size_t)bb * C_ + c0 + cc] = ktile[cc * 33 + bb];
    }
}

// ---------------- k4: per-b radix-select 512 smallest keys --------------------
__device__ __forceinline__ unsigned fmapk(float f) {
    unsigned u = __float_as_uint(f);
    return (u & 0x80000000u) ? ~u : (u | 0x80000000u);
}

__global__ __launch_bounds__(256) void k4_select(const float* __restrict__ keys,
                                                 int* __restrict__ idxlist) {
    const int b = blockIdx.x, t = threadIdx.x;
    __shared__ unsigned hist[256];
    __shared__ unsigned sh_pref, sh_want, sh_nsel;
    if (t == 0) { sh_pref = 0u; sh_want = K_; sh_nsel = 0u; }
    __syncthreads();

    for (int pass = 0; pass < 4; pass++) {
        const int shift = 24 - 8 * pass;
        hist[t] = 0u;
        __syncthreads();
        const unsigned pref = sh_pref;
        for (int c = t; c < C_; c += 256) {
            unsigned u = fmapk(keys[(size_t)b * C_ + c]);
            bool cand = (pass == 0) ? true : ((u >> (shift + 8)) == (pref >> (shift + 8)));
            if (cand) atomicAdd(&hist[(u >> shift) & 255u], 1u);
        }
        __syncthreads();
        if (t == 0) {
            unsigned cum = 0;
            for (int k = 0; k < 256; k++) {
                unsigned h = hist[k];
                if (cum + h >= sh_want) {
                    sh_pref = pref | ((unsigned)k << shift);
                    sh_want -= cum;
                    break;
                }
                cum += h;
            }
        }
        __syncthreads();
    }

    const unsigned Kk = sh_pref, quota = sh_want;
    for (int c = t; c < C_; c += 256) {
        unsigned u = fmapk(keys[(size_t)b * C_ + c]);
        bool take = (u < Kk);
        if (!take && u == Kk) {
            // exact tie handling: take lowest-index ties first (rare; O(C) scan)
            unsigned r = 0;
            for (int j = 0; j < c; j++)
                if (fmapk(keys[(size_t)b * C_ + j]) == Kk) r++;
            take = (r < quota);
        }
        if (take) {
            unsigned s = atomicAdd(&sh_nsel, 1u);
            idxlist[b * K_ + s] = c;
        }
    }
}

// ---------------- k5: total_det = sum over top-512 of exp densities -----------
__global__ __launch_bounds__(256) void k5_det(const float* __restrict__ weight,
                                              const float* __restrict__ mu,
                                              const float* __restrict__ var,
                                              const int* __restrict__ idxlist,
                                              float* __restrict__ total_det) {
    const int b = blockIdx.x >> 3;
    const int sl = blockIdx.x & 7;
    const int t = threadIdx.x;
    const float muv = mu[b * D_ + t];
    const float nh = -0.5f / var[b * D_ + t];
    float acc = 0.f;
    for (int k = 0; k < K_ / 8; k++) {
        int idx = idxlist[b * K_ + sl * (K_ / 8) + k];
        float w = weight[(size_t)idx * D_ + t];
        float df = w - muv;
        acc += __expf(df * df * nh);
    }
    atomicAdd(&total_det[b * D_ + t], acc);
}

// ---------------- k6: final scalar reduction (double) -------------------------
__global__ __launch_bounds__(256) void k6_final(const float* __restrict__ dens,
                                                const float* __restrict__ tot,
                                                const float* __restrict__ ofl,
                                                const float* __restrict__ total_det,
                                                float* __restrict__ out) {
    const int t = threadIdx.x;
    double acc = 0.0;
    for (int i = t; i < B_ * D_; i += 256) {
        double dn = dens[i], tt = tot[i], o = ofl[i];
        double td = fmax((double)total_det[i], 1e-8);
        // sum over c for this (b,d): dens/tot*(C-(C-1)o) - dens/td*(C-1)o
        acc += dn / tt * ((double)C_ - (double)(C_ - 1) * o) - dn / td * ((double)(C_ - 1) * o);
    }
    __shared__ double red[256];
    red[t] = acc;
    __syncthreads();
    for (int s = 128; s > 0; s >>= 1) {
        if (t < s) red[t] += red[t + s];
        __syncthreads();
    }
    if (t == 0) out[0] = (float)(red[0] / ((double)B_ * (double)C_ * (double)D_));
}

extern "C" void kernel_launch(void* const* d_in, const int* in_sizes, int n_in,
                              void* d_out, int out_size, void* d_ws, size_t ws_size,
                              hipStream_t stream) {
    const float* weight = (const float*)d_in[0];
    const float* mu     = (const float*)d_in[1];
    const float* var    = (const float*)d_in[2];
    const float* acd    = (const float*)d_in[3];
    const int*   labels = (const int*)d_in[4];
    // d_in[5] (nontrivial) is all-True by construction -> folded into the math.
    float* out = (float*)d_out;

    char* ws = (char*)d_ws;
    const size_t np = (size_t)B_ * NCH * D_;
    float* psum = (float*)ws;
    float* pm1  = psum + np;
    float* pm2  = pm1 + np;
    float* dens = pm2 + np;
    float* tot  = dens + B_ * D_;
    float* ofl  = tot + B_ * D_;
    float* keys = ofl + B_ * D_;
    int*  idxl  = (int*)(keys + (size_t)B_ * C_);
    float* tdet = (float*)(idxl + B_ * K_);
    // total ws use ~7.3 MB

    hipMemsetAsync(tdet, 0, B_ * D_ * sizeof(float), stream);

    k1_colreduce<<<B_ * NCH, 256, 0, stream>>>(acd, psum, pm1, pm2);
    k2_finalize<<<B_, 256, 0, stream>>>(psum, pm1, pm2, weight, mu, var, labels, dens, tot, ofl);
    k3_keys<<<C_ / CBLK, 256, 0, stream>>>(weight, labels, keys);
    k4_select<<<B_, 256, 0, stream>>>(keys, idxl);
    k5_det<<<B_ * 8, 256, 0, stream>>>(weight, mu, var, idxl, tdet);
    k6_final<<<1, 256, 0, stream>>>(dens, tot, ofl, tdet, out);
}

// Round 2
// 498.245 us; speedup vs baseline: 1.7272x; 1.7272x over previous
//
#include <hip/hip_runtime.h>
#include <cfloat>
#include <cstddef>

#define B_ 32
#define C_ 8192
#define D_ 256
#define K_ 512
#define NCH 64
#define CPB (C_ / NCH) /* 128 c's per chunk */
#define CBLK 16        /* c's per block in key kernel */

// ---------------- k1: column reduce over C (sum, min, 2nd-min) ----------------
__global__ __launch_bounds__(256) void k1_colreduce(const float* __restrict__ acd,
                                                    float* __restrict__ psum,
                                                    float* __restrict__ pm1,
                                                    float* __restrict__ pm2) {
    const int t = threadIdx.x;
    const int blk = blockIdx.x;
    const int b = blk / NCH, ch = blk % NCH;
    const int d4 = t & 63;
    const int coff = t >> 6;

    const float4* src = (const float4*)(acd + ((size_t)b * C_ + (size_t)ch * CPB) * D_);

    float4 s  = make_float4(0.f, 0.f, 0.f, 0.f);
    float4 m1 = make_float4(FLT_MAX, FLT_MAX, FLT_MAX, FLT_MAX);
    float4 m2 = m1;

#define UPD3(f) { s.f += x.f; float mx = fmaxf(m1.f, x.f); m2.f = fminf(m2.f, mx); m1.f = fminf(m1.f, x.f); }
#pragma unroll 4
    for (int r = coff; r < CPB; r += 4) {
        float4 x = src[(size_t)r * 64 + d4];
        UPD3(x) UPD3(y) UPD3(z) UPD3(w)
    }
#undef UPD3

    __shared__ float4 ls[256];
    __shared__ float4 l1[256];
    __shared__ float4 l2[256];
    ls[t] = s; l1[t] = m1; l2[t] = m2;
    __syncthreads();

    if (t < 64) {
        float4 S = ls[t], M1 = l1[t], M2 = l2[t];
#define CMB(f) { S.f += s2.f; float mx = fmaxf(M1.f, a1.f); M2.f = fminf(fminf(M2.f, a2.f), mx); M1.f = fminf(M1.f, a1.f); }
#pragma unroll
        for (int j = 64; j < 256; j += 64) {
            float4 s2 = ls[t + j], a1 = l1[t + j], a2 = l2[t + j];
            CMB(x) CMB(y) CMB(z) CMB(w)
        }
#undef CMB
        size_t o = ((size_t)b * NCH + ch) * 64 + t;
        ((float4*)psum)[o] = S;
        ((float4*)pm1)[o] = M1;
        ((float4*)pm2)[o] = M2;
    }
}

// ---------------- k2: combine chunks; density/total/overly per (b,d) ----------
// Also ORs an "any_overly" flag so the det/top-k path (k3/k4/k5) can be skipped
// entirely when overly == 0 everywhere (its contribution is then exactly 0).
__global__ __launch_bounds__(256) void k2_finalize(const float* __restrict__ psum,
                                                   const float* __restrict__ pm1,
                                                   const float* __restrict__ pm2,
                                                   const float* __restrict__ weight,
                                                   const float* __restrict__ mu,
                                                   const float* __restrict__ var,
                                                   const int* __restrict__ labels,
                                                   float* __restrict__ dens_o,
                                                   float* __restrict__ tot_o,
                                                   float* __restrict__ ofl_o,
                                                   unsigned* __restrict__ flag) {
    const int b = blockIdx.x, d = threadIdx.x;
    float sum = 0.f, m1 = FLT_MAX, m2 = FLT_MAX;
    for (int ch = 0; ch < NCH; ch++) {
        size_t o = ((size_t)b * NCH + ch) * D_ + d;
        float cs = psum[o], c1 = pm1[o], c2 = pm2[o];
        sum += cs;
        m2 = fminf(fminf(m2, c2), fmaxf(m1, c1));
        m1 = fminf(m1, c1);
    }
    const int lab = labels[b];
    const float sw = weight[(size_t)lab * D_ + d];
    const float diff = sw - mu[b * D_ + d];
    const float v = var[b * D_ + d];
    const float dens = expf(-(diff * diff) / (2.0f * v));
    const float tot = fmaxf(sum, 1e-8f);
    const float o_ = (m2 - m1 >= 0.2f * tot) ? 1.0f : 0.0f;
    dens_o[b * D_ + d] = dens;
    tot_o[b * D_ + d] = tot;
    ofl_o[b * D_ + d] = o_;
    if (o_ != 0.0f) atomicOr(flag, 1u);
}

// ---------------- k3: distance keys |w_c|^2 - 2 s_b . w_c  --------------------
__global__ __launch_bounds__(256) void k3_keys(const unsigned* __restrict__ flag,
                                               const float* __restrict__ weight,
                                               const int* __restrict__ labels,
                                               float* __restrict__ keys) {
    if (*flag == 0u) return;
    __shared__ float s_s[32 * 257];
    __shared__ float s_w[CBLK * 257];
    __shared__ float s_wsq[CBLK];
    __shared__ float ktile[CBLK * 33];
    const int t = threadIdx.x;
    const int c0 = blockIdx.x * CBLK;

    for (int i = t; i < 32 * D_; i += 256) {
        int bb = i >> 8, d = i & 255;
        s_s[bb * 257 + d] = weight[(size_t)labels[bb] * D_ + d];
    }
    for (int i = t; i < CBLK * D_; i += 256) {
        int cc = i >> 8, d = i & 255;
        s_w[cc * 257 + d] = weight[(size_t)(c0 + cc) * D_ + d];
    }
    __syncthreads();

    const int b = t & 31, cg = t >> 5;
    const int cc0 = cg, cc1 = cg + 8;
    float acc0 = 0.f, acc1 = 0.f, w0 = 0.f, w1 = 0.f;
    for (int d = 0; d < D_; d++) {
        float sv = s_s[b * 257 + d];
        float wa = s_w[cc0 * 257 + d], wb = s_w[cc1 * 257 + d];
        acc0 += sv * wa;
        acc1 += sv * wb;
        if (b == 0) { w0 += wa * wa; w1 += wb * wb; }
    }
    if (b == 0) { s_wsq[cc0] = w0; s_wsq[cc1] = w1; }
    __syncthreads();
    ktile[cc0 * 33 + b] = s_wsq[cc0] - 2.0f * acc0;
    ktile[cc1 * 33 + b] = s_wsq[cc1] - 2.0f * acc1;
    __syncthreads();
    for (int i = t; i < 32 * CBLK; i += 256) {
        int bb = i >> 4, cc = i & 15;
        keys[(size_t)bb * C_ + c0 + cc] = ktile[cc * 33 + bb];
    }
}

// ---------------- k4: per-b radix-select 512 smallest keys --------------------
__device__ __forceinline__ unsigned fmapk(float f) {
    unsigned u = __float_as_uint(f);
    return (u & 0x80000000u) ? ~u : (u | 0x80000000u);
}

__global__ __launch_bounds__(256) void k4_select(const unsigned* __restrict__ flag,
                                                 const float* __restrict__ keys,
                                                 int* __restrict__ idxlist) {
    if (*flag == 0u) return;
    const int b = blockIdx.x, t = threadIdx.x;
    __shared__ unsigned kl[C_];        // 32 KiB: all keys for this b, mapped
    __shared__ unsigned hist[256];
    __shared__ unsigned scan[256];
    __shared__ unsigned sh_pref, sh_want, sh_nsel;

    for (int c = t; c < C_; c += 256) kl[c] = fmapk(keys[(size_t)b * C_ + c]);
    if (t == 0) { sh_pref = 0u; sh_want = K_; sh_nsel = 0u; }
    __syncthreads();

    for (int pass = 0; pass < 4; pass++) {
        const int shift = 24 - 8 * pass;
        hist[t] = 0u;
        __syncthreads();
        const unsigned pref = sh_pref;
        const unsigned pmask = (pass == 0) ? 0u : (0xFFFFFFFFu << (shift + 8));
        for (int c = t; c < C_; c += 256) {
            unsigned u = kl[c];
            if ((u & pmask) == (pref & pmask)) atomicAdd(&hist[(u >> shift) & 255u], 1u);
        }
        __syncthreads();
        // parallel inclusive prefix over 256 bins (Hillis-Steele)
        unsigned h = hist[t];
        scan[t] = h;
        __syncthreads();
        for (int off = 1; off < 256; off <<= 1) {
            unsigned x = (t >= off) ? scan[t - off] : 0u;
            __syncthreads();
            scan[t] += x;
            __syncthreads();
        }
        const unsigned want = sh_want;
        const unsigned incl = scan[t], excl = incl - h;
        if (incl >= want && excl < want) {  // exactly one t satisfies this
            sh_pref = pref | ((unsigned)t << shift);
            sh_want = want - excl;
        }
        __syncthreads();
    }

    const unsigned Kk = sh_pref, quota = sh_want;
    for (int c = t; c < C_; c += 256) {
        unsigned u = kl[c];
        bool take = (u < Kk);
        if (!take && u == Kk) {
            unsigned r = 0;
            for (int j = 0; j < c; j++)
                if (kl[j] == Kk) r++;
            take = (r < quota);
        }
        if (take) {
            unsigned s = atomicAdd(&sh_nsel, 1u);
            idxlist[b * K_ + s] = c;
        }
    }
}

// ---------------- k5: total_det = sum over top-512 of exp densities -----------
__global__ __launch_bounds__(256) void k5_det(const unsigned* __restrict__ flag,
                                              const float* __restrict__ weight,
                                              const float* __restrict__ mu,
                                              const float* __restrict__ var,
                                              const int* __restrict__ idxlist,
                                              float* __restrict__ total_det) {
    if (*flag == 0u) return;
    const int b = blockIdx.x >> 3;
    const int sl = blockIdx.x & 7;
    const int t = threadIdx.x;
    const float muv = mu[b * D_ + t];
    const float nh = -0.5f / var[b * D_ + t];
    float acc = 0.f;
    for (int k = 0; k < K_ / 8; k++) {
        int idx = idxlist[b * K_ + sl * (K_ / 8) + k];
        float w = weight[(size_t)idx * D_ + t];
        float df = w - muv;
        acc += __expf(df * df * nh);
    }
    atomicAdd(&total_det[b * D_ + t], acc);
}

// ---------------- k6: final scalar reduction (double) -------------------------
// When overly==0 the det term is multiplied by 0; total_det stays memset-0 ->
// td = 1e-8, term = dens/td * 0 = 0 exactly. No dependence on k3/k4/k5.
__global__ __launch_bounds__(256) void k6_final(const float* __restrict__ dens,
                                                const float* __restrict__ tot,
                                                const float* __restrict__ ofl,
                                                const float* __restrict__ total_det,
                                                float* __restrict__ out) {
    const int t = threadIdx.x;
    double acc = 0.0;
    for (int i = t; i < B_ * D_; i += 256) {
        double dn = dens[i], tt = tot[i], o = ofl[i];
        double td = fmax((double)total_det[i], 1e-8);
        acc += dn / tt * ((double)C_ - (double)(C_ - 1) * o) - dn / td * ((double)(C_ - 1) * o);
    }
    __shared__ double red[256];
    red[t] = acc;
    __syncthreads();
    for (int s = 128; s > 0; s >>= 1) {
        if (t < s) red[t] += red[t + s];
        __syncthreads();
    }
    if (t == 0) out[0] = (float)(red[0] / ((double)B_ * (double)C_ * (double)D_));
}

extern "C" void kernel_launch(void* const* d_in, const int* in_sizes, int n_in,
                              void* d_out, int out_size, void* d_ws, size_t ws_size,
                              hipStream_t stream) {
    const float* weight = (const float*)d_in[0];
    const float* mu     = (const float*)d_in[1];
    const float* var    = (const float*)d_in[2];
    const float* acd    = (const float*)d_in[3];
    const int*   labels = (const int*)d_in[4];
    float* out = (float*)d_out;

    char* ws = (char*)d_ws;
    const size_t np = (size_t)B_ * NCH * D_;
    float* psum = (float*)ws;
    float* pm1  = psum + np;
    float* pm2  = pm1 + np;
    float* dens = pm2 + np;
    float* tot  = dens + B_ * D_;
    float* ofl  = tot + B_ * D_;
    float* keys = ofl + B_ * D_;
    int*  idxl  = (int*)(keys + (size_t)B_ * C_);
    float* tdet = (float*)(idxl + B_ * K_);
    unsigned* flag = (unsigned*)(tdet + B_ * D_);

    // zero tdet (B*D floats) and flag (1 u32) in one async memset
    hipMemsetAsync(tdet, 0, B_ * D_ * sizeof(float) + sizeof(unsigned), stream);

    k1_colreduce<<<B_ * NCH, 256, 0, stream>>>(acd, psum, pm1, pm2);
    k2_finalize<<<B_, 256, 0, stream>>>(psum, pm1, pm2, weight, mu, var, labels, dens, tot, ofl, flag);
    k3_keys<<<C_ / CBLK, 256, 0, stream>>>(flag, weight, labels, keys);
    k4_select<<<B_, 256, 0, stream>>>(flag, keys, idxl);
    k5_det<<<B_ * 8, 256, 0, stream>>>(flag, weight, mu, var, idxl, tdet);
    k6_final<<<1, 256, 0, stream>>>(dens, tot, ofl, tdet, out);
}

// Round 4
// 466.214 us; speedup vs baseline: 1.8459x; 1.0687x over previous
//
#include <hip/hip_runtime.h>
#include <cfloat>
#include <cstddef>

#define B_ 32
#define C_ 8192
#define D_ 256
#define K_ 512
#define NCH 64
#define CPB (C_ / NCH) /* 128 c's per chunk */
#define CBLK 16        /* c's per block in key kernel */

typedef float f4n __attribute__((ext_vector_type(4)));  // native vec for nontemporal builtin

// ---------------- k1: column reduce over C (sum, min, 2nd-min) ----------------
// grid = B*NCH blocks, 256 threads. acd is streamed exactly once -> nontemporal.
// Block 0 also zeroes the any_overly flag (consumed by k2 in a later dispatch).
__global__ __launch_bounds__(256) void k1_colreduce(const float* __restrict__ acd,
                                                    float* __restrict__ psum,
                                                    float* __restrict__ pm1,
                                                    float* __restrict__ pm2,
                                                    unsigned* __restrict__ flag) {
    const int t = threadIdx.x;
    const int blk = blockIdx.x;
    if (blk == 0 && t == 0) *flag = 0u;
    const int b = blk / NCH, ch = blk % NCH;
    const int d4 = t & 63;
    const int coff = t >> 6;

    const f4n* src = (const f4n*)(acd + ((size_t)b * C_ + (size_t)ch * CPB) * D_);

    f4n s  = (f4n){0.f, 0.f, 0.f, 0.f};
    f4n m1 = (f4n){FLT_MAX, FLT_MAX, FLT_MAX, FLT_MAX};
    f4n m2 = m1;

#define UPD3(f) { s.f += x.f; float mx = fmaxf(m1.f, x.f); m2.f = fminf(m2.f, mx); m1.f = fminf(m1.f, x.f); }
#pragma unroll 4
    for (int r = coff; r < CPB; r += 4) {
        f4n x = __builtin_nontemporal_load(&src[(size_t)r * 64 + d4]);
        UPD3(x) UPD3(y) UPD3(z) UPD3(w)
    }
#undef UPD3

    __shared__ f4n ls[256];
    __shared__ f4n l1[256];
    __shared__ f4n l2[256];
    ls[t] = s; l1[t] = m1; l2[t] = m2;
    __syncthreads();

    if (t < 64) {
        f4n S = ls[t], M1 = l1[t], M2 = l2[t];
#define CMB(f) { S.f += s2.f; float mx = fmaxf(M1.f, a1.f); M2.f = fminf(fminf(M2.f, a2.f), mx); M1.f = fminf(M1.f, a1.f); }
#pragma unroll
        for (int j = 64; j < 256; j += 64) {
            f4n s2 = ls[t + j], a1 = l1[t + j], a2 = l2[t + j];
            CMB(x) CMB(y) CMB(z) CMB(w)
        }
#undef CMB
        size_t o = ((size_t)b * NCH + ch) * 64 + t;
        ((f4n*)psum)[o] = S;
        ((f4n*)pm1)[o] = M1;
        ((f4n*)pm2)[o] = M2;
    }
}

// ---------------- k2: combine chunks; density/total/overly per (b,d) ----------
// Zeroes total_det (k5 accumulates into it in a later dispatch) and ORs the
// any_overly flag so k3/k4/k5 can early-exit when the det path contributes 0.
__global__ __launch_bounds__(256) void k2_finalize(const float* __restrict__ psum,
                                                   const float* __restrict__ pm1,
                                                   const float* __restrict__ pm2,
                                                   const float* __restrict__ weight,
                                                   const float* __restrict__ mu,
                                                   const float* __restrict__ var,
                                                   const int* __restrict__ labels,
                                                   float* __restrict__ dens_o,
                                                   float* __restrict__ tot_o,
                                                   float* __restrict__ ofl_o,
                                                   float* __restrict__ total_det,
                                                   unsigned* __restrict__ flag) {
    const int b = blockIdx.x, d = threadIdx.x;
    float sum = 0.f, m1 = FLT_MAX, m2 = FLT_MAX;
    for (int ch = 0; ch < NCH; ch++) {
        size_t o = ((size_t)b * NCH + ch) * D_ + d;
        float cs = psum[o], c1 = pm1[o], c2 = pm2[o];
        sum += cs;
        m2 = fminf(fminf(m2, c2), fmaxf(m1, c1));
        m1 = fminf(m1, c1);
    }
    const int lab = labels[b];
    const float sw = weight[(size_t)lab * D_ + d];
    const float diff = sw - mu[b * D_ + d];
    const float v = var[b * D_ + d];
    const float dens = expf(-(diff * diff) / (2.0f * v));
    const float tot = fmaxf(sum, 1e-8f);
    const float o_ = (m2 - m1 >= 0.2f * tot) ? 1.0f : 0.0f;
    dens_o[b * D_ + d] = dens;
    tot_o[b * D_ + d] = tot;
    ofl_o[b * D_ + d] = o_;
    total_det[b * D_ + d] = 0.0f;
    if (o_ != 0.0f) atomicOr(flag, 1u);
}

// ---------------- k3: distance keys |w_c|^2 - 2 s_b . w_c  --------------------
__global__ __launch_bounds__(256) void k3_keys(const unsigned* __restrict__ flag,
                                               const float* __restrict__ weight,
                                               const int* __restrict__ labels,
                                               float* __restrict__ keys) {
    if (*flag == 0u) return;
    __shared__ float s_s[32 * 257];
    __shared__ float s_w[CBLK * 257];
    __shared__ float s_wsq[CBLK];
    __shared__ float ktile[CBLK * 33];
    const int t = threadIdx.x;
    const int c0 = blockIdx.x * CBLK;

    for (int i = t; i < 32 * D_; i += 256) {
        int bb = i >> 8, d = i & 255;
        s_s[bb * 257 + d] = weight[(size_t)labels[bb] * D_ + d];
    }
    for (int i = t; i < CBLK * D_; i += 256) {
        int cc = i >> 8, d = i & 255;
        s_w[cc * 257 + d] = weight[(size_t)(c0 + cc) * D_ + d];
    }
    __syncthreads();

    const int b = t & 31, cg = t >> 5;
    const int cc0 = cg, cc1 = cg + 8;
    float acc0 = 0.f, acc1 = 0.f, w0 = 0.f, w1 = 0.f;
    for (int d = 0; d < D_; d++) {
        float sv = s_s[b * 257 + d];
        float wa = s_w[cc0 * 257 + d], wb = s_w[cc1 * 257 + d];
        acc0 += sv * wa;
        acc1 += sv * wb;
        if (b == 0) { w0 += wa * wa; w1 += wb * wb; }
    }
    if (b == 0) { s_wsq[cc0] = w0; s_wsq[cc1] = w1; }
    __syncthreads();
    ktile[cc0 * 33 + b] = s_wsq[cc0] - 2.0f * acc0;
    ktile[cc1 * 33 + b] = s_wsq[cc1] - 2.0f * acc1;
    __syncthreads();
    for (int i = t; i < 32 * CBLK; i += 256) {
        int bb = i >> 4, cc = i & 15;
        keys[(size_t)bb * C_ + c0 + cc] = ktile[cc * 33 + bb];
    }
}

// ---------------- k4: per-b radix-select 512 smallest keys --------------------
__device__ __forceinline__ unsigned fmapk(float f) {
    unsigned u = __float_as_uint(f);
    return (u & 0x80000000u) ? ~u : (u | 0x80000000u);
}

__global__ __launch_bounds__(256) void k4_select(const unsigned* __restrict__ flag,
                                                 const float* __restrict__ keys,
                                                 int* __restrict__ idxlist) {
    if (*flag == 0u) return;
    const int b = blockIdx.x, t = threadIdx.x;
    __shared__ unsigned kl[C_];        // 32 KiB: all keys for this b, mapped
    __shared__ unsigned hist[256];
    __shared__ unsigned scan[256];
    __shared__ unsigned sh_pref, sh_want, sh_nsel;

    for (int c = t; c < C_; c += 256) kl[c] = fmapk(keys[(size_t)b * C_ + c]);
    if (t == 0) { sh_pref = 0u; sh_want = K_; sh_nsel = 0u; }
    __syncthreads();

    for (int pass = 0; pass < 4; pass++) {
        const int shift = 24 - 8 * pass;
        hist[t] = 0u;
        __syncthreads();
        const unsigned pref = sh_pref;
        const unsigned pmask = (pass == 0) ? 0u : (0xFFFFFFFFu << (shift + 8));
        for (int c = t; c < C_; c += 256) {
            unsigned u = kl[c];
            if ((u & pmask) == (pref & pmask)) atomicAdd(&hist[(u >> shift) & 255u], 1u);
        }
        __syncthreads();
        unsigned h = hist[t];
        scan[t] = h;
        __syncthreads();
        for (int off = 1; off < 256; off <<= 1) {
            unsigned x = (t >= off) ? scan[t - off] : 0u;
            __syncthreads();
            scan[t] += x;
            __syncthreads();
        }
        const unsigned want = sh_want;
        const unsigned incl = scan[t], excl = incl - h;
        if (incl >= want && excl < want) {
            sh_pref = pref | ((unsigned)t << shift);
            sh_want = want - excl;
        }
        __syncthreads();
    }

    const unsigned Kk = sh_pref, quota = sh_want;
    for (int c = t; c < C_; c += 256) {
        unsigned u = kl[c];
        bool take = (u < Kk);
        if (!take && u == Kk) {
            unsigned r = 0;
            for (int j = 0; j < c; j++)
                if (kl[j] == Kk) r++;
            take = (r < quota);
        }
        if (take) {
            unsigned s = atomicAdd(&sh_nsel, 1u);
            idxlist[b * K_ + s] = c;
        }
    }
}

// ---------------- k5: total_det = sum over top-512 of exp densities -----------
__global__ __launch_bounds__(256) void k5_det(const unsigned* __restrict__ flag,
                                              const float* __restrict__ weight,
                                              const float* __restrict__ mu,
                                              const float* __restrict__ var,
                                              const int* __restrict__ idxlist,
                                              float* __restrict__ total_det) {
    if (*flag == 0u) return;
    const int b = blockIdx.x >> 3;
    const int sl = blockIdx.x & 7;
    const int t = threadIdx.x;
    const float muv = mu[b * D_ + t];
    const float nh = -0.5f / var[b * D_ + t];
    float acc = 0.f;
    for (int k = 0; k < K_ / 8; k++) {
        int idx = idxlist[b * K_ + sl * (K_ / 8) + k];
        float w = weight[(size_t)idx * D_ + t];
        float df = w - muv;
        acc += expf(df * df * nh);
    }
    atomicAdd(&total_det[b * D_ + t], acc);
}

// ---------------- k6: final scalar reduction (double) -------------------------
// When overly==0 everywhere: det term is o*(...)=0 exactly; tdet is 0 -> 1e-8
// clamp, multiplied by o=0. No dependence on k3/k4/k5 outputs in that case.
__global__ __launch_bounds__(256) void k6_final(const float* __restrict__ dens,
                                                const float* __restrict__ tot,
                                                const float* __restrict__ ofl,
                                                const float* __restrict__ total_det,
                                                float* __restrict__ out) {
    const int t = threadIdx.x;
    double acc = 0.0;
    for (int i = t; i < B_ * D_; i += 256) {
        double dn = dens[i], tt = tot[i], o = ofl[i];
        double td = fmax((double)total_det[i], 1e-8);
        acc += dn / tt * ((double)C_ - (double)(C_ - 1) * o) - dn / td * ((double)(C_ - 1) * o);
    }
    __shared__ double red[256];
    red[t] = acc;
    __syncthreads();
    for (int s = 128; s > 0; s >>= 1) {
        if (t < s) red[t] += red[t + s];
        __syncthreads();
    }
    if (t == 0) out[0] = (float)(red[0] / ((double)B_ * (double)C_ * (double)D_));
}

extern "C" void kernel_launch(void* const* d_in, const int* in_sizes, int n_in,
                              void* d_out, int out_size, void* d_ws, size_t ws_size,
                              hipStream_t stream) {
    const float* weight = (const float*)d_in[0];
    const float* mu     = (const float*)d_in[1];
    const float* var    = (const float*)d_in[2];
    const float* acd    = (const float*)d_in[3];
    const int*   labels = (const int*)d_in[4];
    float* out = (float*)d_out;

    char* ws = (char*)d_ws;
    const size_t np = (size_t)B_ * NCH * D_;
    float* psum = (float*)ws;
    float* pm1  = psum + np;
    float* pm2  = pm1 + np;
    float* dens = pm2 + np;
    float* tot  = dens + B_ * D_;
    float* ofl  = tot + B_ * D_;
    float* keys = ofl + B_ * D_;
    int*  idxl  = (int*)(keys + (size_t)B_ * C_);
    float* tdet = (float*)(idxl + B_ * K_);
    unsigned* flag = (unsigned*)(tdet + B_ * D_);

    k1_colreduce<<<B_ * NCH, 256, 0, stream>>>(acd, psum, pm1, pm2, flag);
    k2_finalize<<<B_, 256, 0, stream>>>(psum, pm1, pm2, weight, mu, var, labels,
                                        dens, tot, ofl, tdet, flag);
    k3_keys<<<C_ / CBLK, 256, 0, stream>>>(flag, weight, labels, keys);
    k4_select<<<B_, 256, 0, stream>>>(flag, keys, idxl);
    k5_det<<<B_ * 8, 256, 0, stream>>>(flag, weight, mu, var, idxl, tdet);
    k6_final<<<1, 256, 0, stream>>>(dens, tot, ofl, tdet, out);
}

// Round 5
// 463.260 us; speedup vs baseline: 1.8576x; 1.0064x over previous
//
#include <hip/hip_runtime.h>
#include <cfloat>
#include <cstddef>

#define B_ 32
#define C_ 8192
#define D_ 256
#define K_ 512
#define NCH 64
#define CPB (C_ / NCH) /* 128 c's per chunk */

typedef float f4n __attribute__((ext_vector_type(4)));  // native vec for nontemporal builtin

// ---------------- k1: column reduce over C (sum, min, 2nd-min) ----------------
// grid = B*NCH blocks, 256 threads. acd is streamed exactly once -> nontemporal.
// Block 0 also zeroes the any_overly flag (consumed by k2 in a later dispatch).
__global__ __launch_bounds__(256) void k1_colreduce(const float* __restrict__ acd,
                                                    float* __restrict__ psum,
                                                    float* __restrict__ pm1,
                                                    float* __restrict__ pm2,
                                                    unsigned* __restrict__ flag) {
    const int t = threadIdx.x;
    const int blk = blockIdx.x;
    if (blk == 0 && t == 0) *flag = 0u;
    const int b = blk / NCH, ch = blk % NCH;
    const int d4 = t & 63;
    const int coff = t >> 6;

    const f4n* src = (const f4n*)(acd + ((size_t)b * C_ + (size_t)ch * CPB) * D_);

    f4n s  = (f4n){0.f, 0.f, 0.f, 0.f};
    f4n m1 = (f4n){FLT_MAX, FLT_MAX, FLT_MAX, FLT_MAX};
    f4n m2 = m1;

#define UPD3(f) { s.f += x.f; float mx = fmaxf(m1.f, x.f); m2.f = fminf(m2.f, mx); m1.f = fminf(m1.f, x.f); }
#pragma unroll 4
    for (int r = coff; r < CPB; r += 4) {
        f4n x = __builtin_nontemporal_load(&src[(size_t)r * 64 + d4]);
        UPD3(x) UPD3(y) UPD3(z) UPD3(w)
    }
#undef UPD3

    __shared__ f4n ls[256];
    __shared__ f4n l1[256];
    __shared__ f4n l2[256];
    ls[t] = s; l1[t] = m1; l2[t] = m2;
    __syncthreads();

    if (t < 64) {
        f4n S = ls[t], M1 = l1[t], M2 = l2[t];
#define CMB(f) { S.f += s2.f; float mx = fmaxf(M1.f, a1.f); M2.f = fminf(fminf(M2.f, a2.f), mx); M1.f = fminf(M1.f, a1.f); }
#pragma unroll
        for (int j = 64; j < 256; j += 64) {
            f4n s2 = ls[t + j], a1 = l1[t + j], a2 = l2[t + j];
            CMB(x) CMB(y) CMB(z) CMB(w)
        }
#undef CMB
        size_t o = ((size_t)b * NCH + ch) * 64 + t;
        ((f4n*)psum)[o] = S;
        ((f4n*)pm1)[o] = M1;
        ((f4n*)pm2)[o] = M2;
    }
}

// ---------------- k2: combine chunks; density/total/overly per (b,d) ----------
__global__ __launch_bounds__(256) void k2_finalize(const float* __restrict__ psum,
                                                   const float* __restrict__ pm1,
                                                   const float* __restrict__ pm2,
                                                   const float* __restrict__ weight,
                                                   const float* __restrict__ mu,
                                                   const float* __restrict__ var,
                                                   const int* __restrict__ labels,
                                                   float* __restrict__ dens_o,
                                                   float* __restrict__ tot_o,
                                                   float* __restrict__ ofl_o,
                                                   unsigned* __restrict__ flag) {
    const int b = blockIdx.x, d = threadIdx.x;
    float sum = 0.f, m1 = FLT_MAX, m2 = FLT_MAX;
    for (int ch = 0; ch < NCH; ch++) {
        size_t o = ((size_t)b * NCH + ch) * D_ + d;
        float cs = psum[o], c1 = pm1[o], c2 = pm2[o];
        sum += cs;
        m2 = fminf(fminf(m2, c2), fmaxf(m1, c1));
        m1 = fminf(m1, c1);
    }
    const int lab = labels[b];
    const float sw = weight[(size_t)lab * D_ + d];
    const float diff = sw - mu[b * D_ + d];
    const float v = var[b * D_ + d];
    const float dens = expf(-(diff * diff) / (2.0f * v));
    const float tot = fmaxf(sum, 1e-8f);
    const float o_ = (m2 - m1 >= 0.2f * tot) ? 1.0f : 0.0f;
    dens_o[b * D_ + d] = dens;
    tot_o[b * D_ + d] = tot;
    ofl_o[b * D_ + d] = o_;
    if (o_ != 0.0f) atomicOr(flag, 1u);
}

// ------- k345: fused keys + radix-select-512 + total_det, one block per b -----
// Early-exits when no (b,d) has overly!=0 (det path contributes exactly 0).
// Keys live entirely in LDS; no global keys/idx buffers, no atomics on tdet.
__device__ __forceinline__ unsigned fmapk(float f) {
    unsigned u = __float_as_uint(f);
    return (u & 0x80000000u) ? ~u : (u | 0x80000000u);
}

__global__ __launch_bounds__(256) void k345_det(const unsigned* __restrict__ flag,
                                                const float* __restrict__ weight,
                                                const float* __restrict__ mu,
                                                const float* __restrict__ var,
                                                const int* __restrict__ labels,
                                                float* __restrict__ total_det) {
    if (*flag == 0u) return;
    const int b = blockIdx.x, t = threadIdx.x;

    __shared__ unsigned kl[C_];      // 32 KiB mapped keys
    __shared__ float s_s[D_];        // sample weight row for this b
    __shared__ unsigned hist[256];
    __shared__ unsigned scan[256];
    __shared__ int sel[K_];
    __shared__ unsigned sh_pref, sh_want, sh_nsel;

    s_s[t] = weight[(size_t)labels[b] * D_ + t];
    if (t == 0) { sh_pref = 0u; sh_want = K_; sh_nsel = 0u; }
    __syncthreads();

    // keys: |w_c|^2 - 2 s.w_c ; thread t handles c = t, t+256, ...
    for (int c = t; c < C_; c += 256) {
        const f4n* wr = (const f4n*)(weight + (size_t)c * D_);
        const f4n* sr = (const f4n*)s_s;
        float dot = 0.f, nsq = 0.f;
#pragma unroll 8
        for (int d4 = 0; d4 < D_ / 4; d4++) {
            f4n w = wr[d4], sv = sr[d4];
            dot += w.x * sv.x + w.y * sv.y + w.z * sv.z + w.w * sv.w;
            nsq += w.x * w.x + w.y * w.y + w.z * w.z + w.w * w.w;
        }
        kl[c] = fmapk(nsq - 2.0f * dot);
    }
    __syncthreads();

    // 4-pass radix select of the 512th-smallest mapped key
    for (int pass = 0; pass < 4; pass++) {
        const int shift = 24 - 8 * pass;
        hist[t] = 0u;
        __syncthreads();
        const unsigned pref = sh_pref;
        const unsigned pmask = (pass == 0) ? 0u : (0xFFFFFFFFu << (shift + 8));
        for (int c = t; c < C_; c += 256) {
            unsigned u = kl[c];
            if ((u & pmask) == (pref & pmask)) atomicAdd(&hist[(u >> shift) & 255u], 1u);
        }
        __syncthreads();
        unsigned h = hist[t];
        scan[t] = h;
        __syncthreads();
        for (int off = 1; off < 256; off <<= 1) {
            unsigned x = (t >= off) ? scan[t - off] : 0u;
            __syncthreads();
            scan[t] += x;
            __syncthreads();
        }
        const unsigned want = sh_want;
        const unsigned incl = scan[t], excl = incl - h;
        if (incl >= want && excl < want) {   // exactly one t satisfies this
            sh_pref = pref | ((unsigned)t << shift);
            sh_want = want - excl;
        }
        __syncthreads();
    }

    const unsigned Kk = sh_pref, quota = sh_want;
    for (int c = t; c < C_; c += 256) {
        unsigned u = kl[c];
        bool take = (u < Kk);
        if (!take && u == Kk) {
            unsigned r = 0;
            for (int j = 0; j < c; j++)
                if (kl[j] == Kk) r++;
            take = (r < quota);   // lowest-index ties first (jax top_k order)
        }
        if (take) {
            unsigned s = atomicAdd(&sh_nsel, 1u);
            sel[s] = c;
        }
    }
    __syncthreads();

    // total_det[b, d=t] = sum over 512 selected classes of exp densities
    const float muv = mu[b * D_ + t];
    const float nh = -0.5f / var[b * D_ + t];
    float acc = 0.f;
    for (int k = 0; k < K_; k++) {
        float w = weight[(size_t)sel[k] * D_ + t];   // lanes d coalesced
        float df = w - muv;
        acc += expf(df * df * nh);
    }
    total_det[b * D_ + t] = acc;
}

// ---------------- k6: final scalar reduction (double) -------------------------
// det term gated on o: when overly==0 the (poisoned) tdet value is never used.
__global__ __launch_bounds__(256) void k6_final(const float* __restrict__ dens,
                                                const float* __restrict__ tot,
                                                const float* __restrict__ ofl,
                                                const float* __restrict__ total_det,
                                                float* __restrict__ out) {
    const int t = threadIdx.x;
    double acc = 0.0;
    for (int i = t; i < B_ * D_; i += 256) {
        double dn = dens[i], tt = tot[i], o = ofl[i];
        acc += dn / tt * ((double)C_ - (double)(C_ - 1) * o);
        if (o != 0.0) {
            double td = fmax((double)total_det[i], 1e-8);
            acc -= dn / td * ((double)(C_ - 1) * o);
        }
    }
    __shared__ double red[256];
    red[t] = acc;
    __syncthreads();
    for (int s = 128; s > 0; s >>= 1) {
        if (t < s) red[t] += red[t + s];
        __syncthreads();
    }
    if (t == 0) out[0] = (float)(red[0] / ((double)B_ * (double)C_ * (double)D_));
}

extern "C" void kernel_launch(void* const* d_in, const int* in_sizes, int n_in,
                              void* d_out, int out_size, void* d_ws, size_t ws_size,
                              hipStream_t stream) {
    const float* weight = (const float*)d_in[0];
    const float* mu     = (const float*)d_in[1];
    const float* var    = (const float*)d_in[2];
    const float* acd    = (const float*)d_in[3];
    const int*   labels = (const int*)d_in[4];
    float* out = (float*)d_out;

    char* ws = (char*)d_ws;
    const size_t np = (size_t)B_ * NCH * D_;
    float* psum = (float*)ws;
    float* pm1  = psum + np;
    float* pm2  = pm1 + np;
    float* dens = pm2 + np;
    float* tot  = dens + B_ * D_;
    float* ofl  = tot + B_ * D_;
    float* tdet = ofl + B_ * D_;
    unsigned* flag = (unsigned*)(tdet + B_ * D_);

    k1_colreduce<<<B_ * NCH, 256, 0, stream>>>(acd, psum, pm1, pm2, flag);
    k2_finalize<<<B_, 256, 0, stream>>>(psum, pm1, pm2, weight, mu, var, labels,
                                        dens, tot, ofl, flag);
    k345_det<<<B_, 256, 0, stream>>>(flag, weight, mu, var, labels, tdet);
    k6_final<<<1, 256, 0, stream>>>(dens, tot, ofl, tdet, out);
}